// Round 8
// baseline (177.546 us; speedup 1.0000x reference)
//
#include <hip/hip_runtime.h>
#include <math.h>

// Problem dims (fixed by reference)
#define BATCH 32
#define CH    1024     // C == P
#define NPix  784      // H*W = 28*28
#define MMOD  4        // M models, Q == 1
#define NPC   32       // p-chunks (k_nz)
#define PPC   32       // channels per chunk
#define GCH   16       // channels per thread-group (2 groups/block)
#define NF4   196      // float4 per 784-pixel row
#define K1B   512      // k_nz block: 8 waves, 2 groups of 196 active threads

typedef __attribute__((ext_vector_type(4))) _Float16 half4;

__device__ __forceinline__ float wave_reduce(float s) {
    #pragma unroll
    for (int off = 32; off; off >>= 1) s += __shfl_down(s, off, 64);
    return s;
}

// Wave64 sum on the VALU pipe (DPP; verified R6/R7). Full sum lands in lane 63.
__device__ __forceinline__ float dpp_wave_sum(float v) {
    int x;
    x = __builtin_amdgcn_update_dpp(0, __builtin_bit_cast(int, v), 0x111, 0xf, 0xf, true);
    v += __builtin_bit_cast(float, x);
    x = __builtin_amdgcn_update_dpp(0, __builtin_bit_cast(int, v), 0x112, 0xf, 0xf, true);
    v += __builtin_bit_cast(float, x);
    x = __builtin_amdgcn_update_dpp(0, __builtin_bit_cast(int, v), 0x114, 0xf, 0xf, true);
    v += __builtin_bit_cast(float, x);
    x = __builtin_amdgcn_update_dpp(0, __builtin_bit_cast(int, v), 0x118, 0xf, 0xf, true);
    v += __builtin_bit_cast(float, x);
    x = __builtin_amdgcn_update_dpp(0, __builtin_bit_cast(int, v), 0x142, 0xa, 0xf, true);
    v += __builtin_bit_cast(float, x);
    x = __builtin_amdgcn_update_dpp(0, __builtin_bit_cast(int, v), 0x143, 0xc, 0xf, true);
    v += __builtin_bit_cast(float, x);
    return v;
}

// Single-pass norms + z-partials. Block (b,pc) owns 32 channels via two
// 196-thread groups of 16 channels each (keeps xv[16] float4 = 64 VGPR/thread,
// 16B/lane loads — R7's VMEM-issue fix). Group 1 funnels its z accumulators
// through LDS; group 0 adds and stores ONE fp16 z-partial per chunk:
// zpart shrinks 25.7MB fp32 (R7) -> 6.4MB fp16.
__global__ __launch_bounds__(K1B) void k_nz(const float* __restrict__ x,
                                            const float* __restrict__ Wm,
                                            float* __restrict__ inv_norm,
                                            half4* __restrict__ zpart) {
    __shared__ float sq_l[PPC][4];
    __shared__ float4 wl4[PPC];
    __shared__ float4 zl[NF4][MMOD];   // group-1 partials, 12.5 KB
    const int blk = blockIdx.x;
    const int b  = blk >> 5;         // / NPC
    const int pc = blk & (NPC - 1);
    const int t = threadIdx.x;
    const int g = t >> 8;            // thread-group 0/1
    const int lt = t & 255;
    const int gwv = (t >> 6) & 3;    // wave index within group
    const int lane = t & 63;
    const bool act = lt < NF4;
    const float4* xb4 = (const float4*)(x + ((size_t)b * CH + (size_t)pc * PPC) * NPix);
    const int tt = act ? lt : 0;

    float4 xv[GCH];
    #pragma unroll
    for (int pp = 0; pp < GCH; pp++)
        xv[pp] = xb4[(g * GCH + pp) * NF4 + tt];   // 16B/lane, coalesced

    #pragma unroll
    for (int pp = 0; pp < GCH; pp++) {
        float4 v = xv[pp];
        float s = act ? (v.x*v.x + v.y*v.y + v.z*v.z + v.w*v.w) : 0.f;
        s = dpp_wave_sum(s);
        if (lane == 63) sq_l[g * GCH + pp][gwv] = s;
    }
    __syncthreads();

    if (t < PPC) {
        const float s = sq_l[t][0] + sq_l[t][1] + sq_l[t][2] + sq_l[t][3];
        const float inv = 1.f / fmaxf(sqrtf(s), 1e-10f);
        const int p = pc * PPC + t;
        inv_norm[b * CH + p] = inv;
        float4 w4;
        w4.x = Wm[0 * CH + p] * inv;
        w4.y = Wm[1 * CH + p] * inv;
        w4.z = Wm[2 * CH + p] * inv;
        w4.w = Wm[3 * CH + p] * inv;
        wl4[t] = w4;
    }
    __syncthreads();

    float4 a0 = {0,0,0,0}, a1 = {0,0,0,0}, a2 = {0,0,0,0}, a3 = {0,0,0,0};
    if (act) {
        #pragma unroll
        for (int pp = 0; pp < GCH; pp++) {
            const float4 w = wl4[g * GCH + pp];  // ds_read_b128 broadcast
            const float4 v = xv[pp];
            a0.x += w.x*v.x; a0.y += w.x*v.y; a0.z += w.x*v.z; a0.w += w.x*v.w;
            a1.x += w.y*v.x; a1.y += w.y*v.y; a1.z += w.y*v.z; a1.w += w.y*v.w;
            a2.x += w.z*v.x; a2.y += w.z*v.y; a2.z += w.z*v.z; a2.w += w.z*v.w;
            a3.x += w.w*v.x; a3.y += w.w*v.y; a3.z += w.w*v.z; a3.w += w.w*v.w;
        }
        if (g == 1) {
            zl[lt][0] = a0; zl[lt][1] = a1; zl[lt][2] = a2; zl[lt][3] = a3;
        }
    }
    __syncthreads();
    if (g == 0 && act) {
        float4 b0 = zl[lt][0], b1 = zl[lt][1], b2 = zl[lt][2], b3 = zl[lt][3];
        a0.x += b0.x; a0.y += b0.y; a0.z += b0.z; a0.w += b0.w;
        a1.x += b1.x; a1.y += b1.y; a1.z += b1.z; a1.w += b1.w;
        a2.x += b2.x; a2.y += b2.y; a2.z += b2.z; a2.w += b2.w;
        a3.x += b3.x; a3.y += b3.y; a3.z += b3.z; a3.w += b3.w;
        half4* zp = zpart + ((size_t)blk * MMOD) * NF4;
        half4 h0 = { (_Float16)a0.x, (_Float16)a0.y, (_Float16)a0.z, (_Float16)a0.w };
        half4 h1 = { (_Float16)a1.x, (_Float16)a1.y, (_Float16)a1.z, (_Float16)a1.w };
        half4 h2 = { (_Float16)a2.x, (_Float16)a2.y, (_Float16)a2.z, (_Float16)a2.w };
        half4 h3 = { (_Float16)a3.x, (_Float16)a3.y, (_Float16)a3.z, (_Float16)a3.w };
        zp[0 * NF4 + lt] = h0;
        zp[1 * NF4 + lt] = h1;
        zp[2 * NF4 + lt] = h2;
        zp[3 * NF4 + lt] = h3;
    }
}

// Merged k_gh + k_h: one block per b (256 thr, t<196 owns 4 pixels).
// z = sum over 32 fp16 chunks; g = sigmoid; s2 per m (block reduce);
// h = sum_m g/s2. Reads 200KB/block from L2/L3.
__global__ __launch_bounds__(256) void k_gh(const half4* __restrict__ zpart,
                                            float* __restrict__ h) {
    __shared__ float red[4][MMOD];
    __shared__ float s2s[MMOD];
    const int b = blockIdx.x;
    const int t = threadIdx.x;
    const int wv = t >> 6, lane = t & 63;
    const bool act = t < NF4;
    const int tt = act ? t : 0;

    float4 g4[MMOD];
    #pragma unroll
    for (int m = 0; m < MMOD; m++) {
        float4 z = {0,0,0,0};
        #pragma unroll 8
        for (int pc = 0; pc < NPC; pc++) {
            half4 v = zpart[(((size_t)(b * NPC + pc)) * MMOD + m) * NF4 + tt];
            z.x += (float)v.x; z.y += (float)v.y; z.z += (float)v.z; z.w += (float)v.w;
        }
        float4 gg;
        gg.x = 1.f / (1.f + expf(-z.x));
        gg.y = 1.f / (1.f + expf(-z.y));
        gg.z = 1.f / (1.f + expf(-z.z));
        gg.w = 1.f / (1.f + expf(-z.w));
        if (!act) gg = (float4){0,0,0,0};
        g4[m] = gg;
        float s = dpp_wave_sum(gg.x*gg.x + gg.y*gg.y + gg.z*gg.z + gg.w*gg.w);
        if (lane == 63) red[wv][m] = s;
    }
    __syncthreads();
    if (t < MMOD) {
        float s = red[0][t] + red[1][t] + red[2][t] + red[3][t];
        s2s[t] = fmaxf(s, 1e-30f);
    }
    __syncthreads();
    if (act) {
        float4 hv = {0,0,0,0};
        #pragma unroll
        for (int m = 0; m < MMOD; m++) {
            const float r = 1.f / s2s[m];
            hv.x += g4[m].x * r; hv.y += g4[m].y * r;
            hv.z += g4[m].z * r; hv.w += g4[m].w * r;
        }
        ((float4*)(h + (size_t)b * NPix))[t] = hv;
    }
}

// out[b,p] = inv_norm[b,p] * dot(x[b,p,:], h[b,:]). One wave per row,
// float4 throughout (near L3-stream-bound since R4).
__global__ __launch_bounds__(256) void k_out(const float* __restrict__ x,
                                             const float* __restrict__ h,
                                             const float* __restrict__ inv_norm,
                                             float* __restrict__ out) {
    const int r = blockIdx.x * 4 + (threadIdx.x >> 6);  // r in [0, 32768)
    const int lane = threadIdx.x & 63;
    const int b = r >> 10;
    const float4* x4 = (const float4*)(x + (size_t)r * NPix);
    const float4* h4 = (const float4*)(h + (size_t)b * NPix);
    float s = 0.f;
    #pragma unroll
    for (int i = 0; i < 3; i++) {
        float4 xv = x4[i * 64 + lane];
        float4 hv = h4[i * 64 + lane];
        s += xv.x*hv.x + xv.y*hv.y + xv.z*hv.z + xv.w*hv.w;
    }
    if (lane < 4) {
        float4 xv = x4[192 + lane];
        float4 hv = h4[192 + lane];
        s += xv.x*hv.x + xv.y*hv.y + xv.z*hv.z + xv.w*hv.w;
    }
    s = wave_reduce(s);
    if (lane == 0) {
        float v = s * inv_norm[r];
        // nan_to_num semantics: nan->0, +/-inf -> +/-FLT_MAX
        if (!(v == v)) v = 0.f;
        v = fminf(fmaxf(v, -3.402823466e+38f), 3.402823466e+38f);
        out[r] = v;
    }
}

extern "C" void kernel_launch(void* const* d_in, const int* in_sizes, int n_in,
                              void* d_out, int out_size, void* d_ws, size_t ws_size,
                              hipStream_t stream) {
    const float* x  = (const float*)d_in[0];   // [32,1024,28,28]
    const float* Wm = (const float*)d_in[1];   // [4,1,1024]
    float* out = (float*)d_out;                // [32,1024]
    float* wsf = (float*)d_ws;

    float* inv_norm = wsf;                               // 32768 floats
    float* h        = inv_norm + BATCH * CH;             // 25088 floats
    half4* zpart    = (half4*)(h + BATCH * NPix);        // 32*32*4*196 half4 = 6.4MB

    k_nz<<<BATCH * NPC, K1B, 0, stream>>>(x, Wm, inv_norm, zpart);
    k_gh<<<BATCH, 256, 0, stream>>>(zpart, h);
    k_out<<<BATCH * CH / 4, 256, 0, stream>>>(x, h, inv_norm, out);
}